// Round 8
// baseline (576.764 us; speedup 1.0000x reference)
//
#include <hip/hip_runtime.h>

#define DEVINL __device__ __forceinline__
#define BCAP 64   // bucket capacity per node; deg~Poisson(12.8), P(>64)~3e-23
#define NREP 64   // hsum atomic replicas (contention / 64)

typedef __attribute__((ext_vector_type(8))) short short8;
typedef __attribute__((ext_vector_type(4))) float f32x4;
typedef __attribute__((ext_vector_type(4))) unsigned short ushort4v;

DEVINL unsigned short f2bf(float f) {  // RNE float->bf16
    unsigned u = __float_as_uint(f);
    u += 0x7fffu + ((u >> 16) & 1u);
    return (unsigned short)(u >> 16);
}
DEVINL float bf2f(unsigned short s) { return __uint_as_float(((unsigned)s) << 16); }

// blocks 0..63: transpose + bf16-convert weights (WT[col][k] layouts).
// blocks 64..95: zero cnt | hsumR | done (replaces hipMemsetAsync).
__global__ __launch_bounds__(256) void k_w(
    const float* __restrict__ Wenc, const float* __restrict__ WM,
    const float* __restrict__ WU,
    unsigned short* __restrict__ WencT, unsigned short* __restrict__ WM1T,
    unsigned short* __restrict__ WM2T, unsigned short* __restrict__ WUT,
    int* __restrict__ zbase, int zn)
{
    if (blockIdx.x < 64) {
        int tid = blockIdx.x * 256 + threadIdx.x;
        const int nt = 64 * 256;
        for (int i = tid; i < 128 * 128; i += nt) {
            int c = i >> 7, k = i & 127;
            WencT[c * 128 + k] = f2bf(Wenc[(1 + k) * 128 + c]);  // rows 1..128
            WM1T[c * 128 + k]  = f2bf(WM[k * 128 + c]);
            WM2T[c * 128 + k]  = f2bf(WM[(128 + k) * 128 + c]);
        }
        for (int i = tid; i < 128 * 256; i += nt) {
            int c = i >> 8, k = i & 255;
            WUT[c * 256 + k] = f2bf(WU[k * 128 + c]);
        }
    } else {
        for (int i = (blockIdx.x - 64) * 256 + threadIdx.x; i < zn; i += 32 * 256)
            zbase[i] = 0;
    }
}

// ---- MFMA structure: block = 16 nodes, 4 waves split the 128 output cols
// (wave w -> t8 in {2w,2w+1} -> cols [32w,32w+32)).
// D: node = lane&15, col = t8*16 + (lane>>4)*4 + r.

// blocks [0,nzq): z = relu([x,pre_h]@W_enc+b) -> zb;  Q = z@WM2 -> Qb.
// blocks [nzq,..): edge bucket scatter (independent work, overlapped).
__global__ __launch_bounds__(256) void k_zq(
    const float* __restrict__ x, const float* __restrict__ preh,
    const unsigned short* __restrict__ WencT, const float* __restrict__ Wenc,
    const float* __restrict__ benc, const unsigned short* __restrict__ WM2T,
    unsigned short* __restrict__ zb, unsigned short* __restrict__ Qb,
    int N, int nzq,
    const int* __restrict__ ei, const float* __restrict__ attr,
    int* __restrict__ cnt, int2* __restrict__ bucket, int E)
{
    if ((int)blockIdx.x >= nzq) {  // ---- scatter part
        int e = ((int)blockIdx.x - nzq) * 256 + threadIdx.x;
        if (e >= E) return;
        int src = ei[e];
        int dst = ei[E + e];
        float a = attr[e];
        int slot = atomicAdd(&cnt[dst], 1);
        if (slot < BCAP)
            bucket[(size_t)dst * BCAP + slot] = make_int2(src, __float_as_int(a));
        return;
    }
    __shared__ __align__(16) unsigned short zl[16][136];
    int t = threadIdx.x;
    int wave = t >> 6, lane = t & 63;
    int m = lane & 15, quad = lane >> 4;
    int node = (int)blockIdx.x * 16 + m;
    bool valid = node < N;
    int nodec = min(node, N - 1);
    // ---- phase A: z tile
    f32x4 acc[2] = {(f32x4)0.f, (f32x4)0.f};
    const float* arow = preh + (size_t)nodec * 128;
#pragma unroll
    for (int kc = 0; kc < 4; ++kc) {
        int k0 = kc * 32 + quad * 8;
        float4 f0 = *(const float4*)(arow + k0);
        float4 f1 = *(const float4*)(arow + k0 + 4);
        short8 bfrag;
        bfrag[0] = (short)f2bf(f0.x); bfrag[1] = (short)f2bf(f0.y);
        bfrag[2] = (short)f2bf(f0.z); bfrag[3] = (short)f2bf(f0.w);
        bfrag[4] = (short)f2bf(f1.x); bfrag[5] = (short)f2bf(f1.y);
        bfrag[6] = (short)f2bf(f1.z); bfrag[7] = (short)f2bf(f1.w);
#pragma unroll
        for (int tt = 0; tt < 2; ++tt) {
            int t8 = wave * 2 + tt;
            short8 afrag = *(const short8*)(WencT + (size_t)(t8 * 16 + m) * 128 + k0);
            acc[tt] = __builtin_amdgcn_mfma_f32_16x16x32_bf16(afrag, bfrag, acc[tt], 0, 0, 0);
        }
    }
    float xv = x[nodec];
#pragma unroll
    for (int tt = 0; tt < 2; ++tt) {
        int col = (wave * 2 + tt) * 16 + quad * 4;
        float4 w0v = *(const float4*)(Wenc + col);  // row 0 of W_enc = x weights
        float4 bv  = *(const float4*)(benc + col);
        ushort4v o;
        o[0] = f2bf(fmaxf(acc[tt][0] + xv * w0v.x + bv.x, 0.f));
        o[1] = f2bf(fmaxf(acc[tt][1] + xv * w0v.y + bv.y, 0.f));
        o[2] = f2bf(fmaxf(acc[tt][2] + xv * w0v.z + bv.z, 0.f));
        o[3] = f2bf(fmaxf(acc[tt][3] + xv * w0v.w + bv.w, 0.f));
        if (valid) *(ushort4v*)(zb + (size_t)node * 128 + col) = o;
        *(ushort4v*)&zl[m][col] = o;  // stage for phase B
    }
    __syncthreads();
    // ---- phase B: Q from LDS z
    f32x4 aQ[2] = {(f32x4)0.f, (f32x4)0.f};
#pragma unroll
    for (int kc = 0; kc < 4; ++kc) {
        int k0 = kc * 32 + quad * 8;
        short8 bfrag = *(const short8*)&zl[m][k0];
#pragma unroll
        for (int tt = 0; tt < 2; ++tt) {
            int t8 = wave * 2 + tt;
            short8 a2 = *(const short8*)(WM2T + (size_t)(t8 * 16 + m) * 128 + k0);
            aQ[tt] = __builtin_amdgcn_mfma_f32_16x16x32_bf16(a2, bfrag, aQ[tt], 0, 0, 0);
        }
    }
    if (!valid) return;
    unsigned short* qrow = Qb + (size_t)node * 128;
#pragma unroll
    for (int tt = 0; tt < 2; ++tt) {
        int col = (wave * 2 + tt) * 16 + quad * 4;
        ushort4v oq;
        oq[0] = f2bf(aQ[tt][0]); oq[1] = f2bf(aQ[tt][1]);
        oq[2] = f2bf(aQ[tt][2]); oq[3] = f2bf(aQ[tt][3]);
        *(ushort4v*)(qrow + col) = oq;
    }
}

// Fused: bucket->LDS staging; gather-max; P GEMM (from z regs) + combine ->
// agg LDS; h = relu([z|agg]@W_U+b); y + hsum epilogues; last block: tau.
__global__ __launch_bounds__(256) void k_aggh(
    const unsigned short* __restrict__ zb, const unsigned short* __restrict__ Qb,
    const int2* __restrict__ bucket, const int* __restrict__ cnt,
    const float* __restrict__ w3, const float* __restrict__ bM,
    const unsigned short* __restrict__ WUT, const unsigned short* __restrict__ WM1T,
    const float* __restrict__ bU, const float* __restrict__ Wd,
    const float* __restrict__ bd, const float* __restrict__ Wterm,
    const float* __restrict__ bterm,
    float* __restrict__ h, float* __restrict__ y, float* __restrict__ hsumR,
    unsigned* __restrict__ done, float* __restrict__ tau, int N)
{
    __shared__ int degs[16];
    __shared__ __align__(16) int2 eb[16][BCAP];
    __shared__ __align__(16) float mac[16][132];
    __shared__ __align__(16) unsigned short al[16][136];
    __shared__ float ys[4][16];
    __shared__ float hsb[128];
    __shared__ float sd[128];
    __shared__ unsigned lastv;

    int t = threadIdx.x;
    int bid16 = (int)blockIdx.x * 16;
    int wave = t >> 6, lane = t & 63;
    int m = lane & 15, quad = lane >> 4;
    int node = bid16 + m;
    bool valid = node < N;
    int nodec = min(node, N - 1);

    // issue z row loads early; reused by P GEMM, h GEMM, and y's z-term
    const unsigned short* arow = zb + (size_t)nodec * 128;
    short8 zfr[4];
#pragma unroll
    for (int kc = 0; kc < 4; ++kc)
        zfr[kc] = *(const short8*)(arow + kc * 32 + quad * 8);

    if (t < 16) degs[t] = min(cnt[min(bid16 + t, N - 1)], BCAP);
    __syncthreads();
    // stage bucket entries (coalesced, independent loads)
    for (int idx = t; idx < 16 * BCAP; idx += 256) {
        int nd = idx >> 6, sl = idx & (BCAP - 1);
        if (sl < degs[nd])
            eb[nd][sl] = bucket[(size_t)min(bid16 + nd, N - 1) * BCAP + sl];
    }
    __syncthreads();
    // gather-max: 16 threads/node, 8 cols each; entry addrs come from LDS
    {
        int il = t >> 4, c0 = (t & 15) * 8;
        int deg = degs[il];
        float w[8];
        {
            float4 wa = *(const float4*)(w3 + c0), wb = *(const float4*)(w3 + c0 + 4);
            w[0]=wa.x; w[1]=wa.y; w[2]=wa.z; w[3]=wa.w;
            w[4]=wb.x; w[5]=wb.y; w[6]=wb.z; w[7]=wb.w;
        }
        const float NI = __uint_as_float(0xff800000u);
        float a8[8];
#pragma unroll
        for (int u = 0; u < 8; ++u) a8[u] = NI;
        int j = 0;
        for (; j + 7 < deg; j += 8) {
            int2 e[8]; short8 q[8];
#pragma unroll
            for (int b = 0; b < 8; ++b) e[b] = eb[il][j + b];
#pragma unroll
            for (int b = 0; b < 8; ++b)
                q[b] = *(const short8*)(Qb + (size_t)e[b].x * 128 + c0);
#pragma unroll
            for (int b = 0; b < 8; ++b) {
                float a = __int_as_float(e[b].y);
#pragma unroll
                for (int u = 0; u < 8; ++u)
                    a8[u] = fmaxf(a8[u], fmaf(a, w[u], bf2f((unsigned short)q[b][u])));
            }
        }
        for (; j + 3 < deg; j += 4) {
            int2 e[4]; short8 q[4];
#pragma unroll
            for (int b = 0; b < 4; ++b) e[b] = eb[il][j + b];
#pragma unroll
            for (int b = 0; b < 4; ++b)
                q[b] = *(const short8*)(Qb + (size_t)e[b].x * 128 + c0);
#pragma unroll
            for (int b = 0; b < 4; ++b) {
                float a = __int_as_float(e[b].y);
#pragma unroll
                for (int u = 0; u < 8; ++u)
                    a8[u] = fmaxf(a8[u], fmaf(a, w[u], bf2f((unsigned short)q[b][u])));
            }
        }
        for (; j < deg; ++j) {
            int2 e0 = eb[il][j];
            float a = __int_as_float(e0.y);
            short8 q0 = *(const short8*)(Qb + (size_t)e0.x * 128 + c0);
#pragma unroll
            for (int u = 0; u < 8; ++u)
                a8[u] = fmaxf(a8[u], fmaf(a, w[u], bf2f((unsigned short)q0[u])));
        }
        *(f32x4*)&mac[il][c0]     = *(f32x4*)&a8[0];
        *(f32x4*)&mac[il][c0 + 4] = *(f32x4*)&a8[4];
    }
    __syncthreads();
    // P GEMM from z regs; combine agg = relu(P + bM + mac) -> al (bf16)
    {
        f32x4 accP[2] = {(f32x4)0.f, (f32x4)0.f};
#pragma unroll
        for (int kc = 0; kc < 4; ++kc) {
            int k0 = kc * 32 + quad * 8;
#pragma unroll
            for (int tt = 0; tt < 2; ++tt) {
                int t8 = wave * 2 + tt;
                short8 afrag = *(const short8*)(WM1T + (size_t)(t8 * 16 + m) * 128 + k0);
                accP[tt] = __builtin_amdgcn_mfma_f32_16x16x32_bf16(afrag, zfr[kc], accP[tt], 0, 0, 0);
            }
        }
#pragma unroll
        for (int tt = 0; tt < 2; ++tt) {
            int col = (wave * 2 + tt) * 16 + quad * 4;
            float4 bmv = *(const float4*)(bM + col);
            float4 mv  = *(const float4*)&mac[m][col];
            ushort4v o;  // deg==0: mac=-inf -> relu 0 (matches ref)
            o[0] = f2bf(fmaxf(accP[tt][0] + bmv.x + mv.x, 0.f));
            o[1] = f2bf(fmaxf(accP[tt][1] + bmv.y + mv.y, 0.f));
            o[2] = f2bf(fmaxf(accP[tt][2] + bmv.z + mv.z, 0.f));
            o[3] = f2bf(fmaxf(accP[tt][3] + bmv.w + mv.w, 0.f));
            *(ushort4v*)&al[m][col] = o;
        }
    }
    __syncthreads();
    // h GEMM (K=256: z from regs, agg from LDS) + fused epilogues
    f32x4 acc[2] = {(f32x4)0.f, (f32x4)0.f};
    float py = 0.f;
#pragma unroll
    for (int kc = 0; kc < 8; ++kc) {
        int k0 = kc * 32 + quad * 8;
        short8 bfrag;
        if (kc < 4) {
            bfrag = zfr[kc];
            if (wave == 0) {  // z·Wd[:128] term (each (kc,quad) k-slice once)
                float4 wa = *(const float4*)(Wd + k0);
                float4 wb = *(const float4*)(Wd + k0 + 4);
                py += bf2f((unsigned short)bfrag[0]) * wa.x
                    + bf2f((unsigned short)bfrag[1]) * wa.y
                    + bf2f((unsigned short)bfrag[2]) * wa.z
                    + bf2f((unsigned short)bfrag[3]) * wa.w
                    + bf2f((unsigned short)bfrag[4]) * wb.x
                    + bf2f((unsigned short)bfrag[5]) * wb.y
                    + bf2f((unsigned short)bfrag[6]) * wb.z
                    + bf2f((unsigned short)bfrag[7]) * wb.w;
            }
        } else {
            bfrag = *(const short8*)&al[m][(kc - 4) * 32 + quad * 8];
        }
#pragma unroll
        for (int tt = 0; tt < 2; ++tt) {
            int t8 = wave * 2 + tt;
            short8 afrag = *(const short8*)(WUT + (size_t)(t8 * 16 + m) * 256 + k0);
            acc[tt] = __builtin_amdgcn_mfma_f32_16x16x32_bf16(afrag, bfrag, acc[tt], 0, 0, 0);
        }
    }
    const float* Wdh = Wd + 128;
    float* orow = h + (size_t)nodec * 128;
#pragma unroll
    for (int tt = 0; tt < 2; ++tt) {
        int col = (wave * 2 + tt) * 16 + quad * 4;
        float4 bv = *(const float4*)(bU + col);
        float4 o;  // zeroed for invalid nodes so hsum stays exact
        o.x = valid ? fmaxf(acc[tt][0] + bv.x, 0.f) : 0.f;
        o.y = valid ? fmaxf(acc[tt][1] + bv.y, 0.f) : 0.f;
        o.z = valid ? fmaxf(acc[tt][2] + bv.z, 0.f) : 0.f;
        o.w = valid ? fmaxf(acc[tt][3] + bv.w, 0.f) : 0.f;
        if (valid) *(float4*)(orow + col) = o;
        float4 wd = *(const float4*)(Wdh + col);
        py += o.x * wd.x + o.y * wd.y + o.z * wd.z + o.w * wd.w;
        float4 s = o;  // sum over the 16 m-lanes (same cols, different nodes)
#pragma unroll
        for (int mask = 1; mask <= 8; mask <<= 1) {
            s.x += __shfl_xor(s.x, mask, 64);
            s.y += __shfl_xor(s.y, mask, 64);
            s.z += __shfl_xor(s.z, mask, 64);
            s.w += __shfl_xor(s.w, mask, 64);
        }
        if (m == 0) *(float4*)&hsb[col] = s;  // (t8,quad) slots disjoint
    }
    py += __shfl_xor(py, 16, 64);
    py += __shfl_xor(py, 32, 64);
    if (lane < 16) ys[wave][lane] = py;
    __syncthreads();
    if (t < 16 && bid16 + t < N)
        y[bid16 + t] = ys[0][t] + ys[1][t] + ys[2][t] + ys[3][t] + bd[0];
    if (t < 128)
        atomicAdd(&hsumR[((int)blockIdx.x & (NREP - 1)) * 128 + t], hsb[t]);
    // ---- fused tau: last block to finish reduces hsumR
    __threadfence();
    if (t == 0) lastv = atomicAdd(done, 1u);
    __syncthreads();
    if (lastv == gridDim.x - 1) {
        if (t < 128) {
            float s = 0.f;
#pragma unroll
            for (int r = 0; r < NREP; ++r)
                s += atomicAdd(&hsumR[r * 128 + t], 0.0f);  // coherent read
            sd[t] = s * (1.f / (float)N) * (Wterm[t] + Wterm[128 + t]);
        }
        __syncthreads();
        for (int o2 = 64; o2 > 0; o2 >>= 1) {
            if (t < o2) sd[t] += sd[t + o2];
            __syncthreads();
        }
        if (t == 0) tau[0] = sd[0] + bterm[0];
    }
}

extern "C" void kernel_launch(void* const* d_in, const int* in_sizes, int n_in,
                              void* d_out, int out_size, void* d_ws, size_t ws_size,
                              hipStream_t stream)
{
    const float* x     = (const float*)d_in[0];
    const float* preh  = (const float*)d_in[1];
    const int*   ei    = (const int*)d_in[2];
    const float* attr  = (const float*)d_in[3];
    const float* Wenc  = (const float*)d_in[4];
    const float* benc  = (const float*)d_in[5];
    const float* WM    = (const float*)d_in[6];
    const float* bM    = (const float*)d_in[7];
    const float* WU    = (const float*)d_in[8];
    const float* bU    = (const float*)d_in[9];
    const float* Wd    = (const float*)d_in[10];
    const float* bd    = (const float*)d_in[11];
    const float* Wterm = (const float*)d_in[12];
    const float* bterm = (const float*)d_in[13];
    int N = in_sizes[0];
    int E = in_sizes[3];

    char* wp = (char*)d_ws;
    unsigned short* zb    = (unsigned short*)wp; wp += (size_t)N * 128 * 2;
    unsigned short* Qb    = (unsigned short*)wp; wp += (size_t)N * 128 * 2;
    int2*           bucket= (int2*)wp;           wp += (size_t)N * BCAP * 8;
    int*            cnt   = (int*)wp;            wp += (size_t)N * 4;
    float*          hsumR = (float*)wp;          wp += NREP * 128 * 4;
    unsigned*       done  = (unsigned*)wp;       wp += 4;
    unsigned short* WencT = (unsigned short*)wp; wp += 128 * 128 * 2;
    unsigned short* WM1T  = (unsigned short*)wp; wp += 128 * 128 * 2;
    unsigned short* WM2T  = (unsigned short*)wp; wp += 128 * 128 * 2;
    unsigned short* WUT   = (unsigned short*)wp; wp += 128 * 256 * 2;

    float* hout = (float*)d_out;
    float* yout = hout + (size_t)N * 128;
    float* tau  = yout + N;

    int nb16 = (N + 15) / 16;
    int sb = (E + 255) / 256;
    int zn = N + NREP * 128 + 1;  // cnt | hsumR | done (contiguous ints)

    k_w<<<96, 256, 0, stream>>>(Wenc, WM, WU, WencT, WM1T, WM2T, WUT,
                                cnt, zn);
    k_zq<<<nb16 + sb, 256, 0, stream>>>(x, preh, WencT, Wenc, benc, WM2T,
                                        zb, Qb, N, nb16,
                                        ei, attr, cnt, bucket, E);
    k_aggh<<<nb16, 256, 0, stream>>>(zb, Qb, bucket, cnt, WM + 256 * 128, bM,
                                     WUT, WM1T, bU, Wd, bd, Wterm, bterm,
                                     hout, yout, hsumR, done, tau, N);
}

// Round 9
// 260.037 us; speedup vs baseline: 2.2180x; 2.2180x over previous
//
#include <hip/hip_runtime.h>

#define DEVINL __device__ __forceinline__
#define BCAP 64   // bucket capacity per node; deg~Poisson(12.8), P(>64)~3e-23
#define NREP 64   // hsum atomic replicas (contention / 64)

typedef __attribute__((ext_vector_type(8))) short short8;
typedef __attribute__((ext_vector_type(4))) float f32x4;
typedef __attribute__((ext_vector_type(4))) unsigned short ushort4v;

DEVINL unsigned short f2bf(float f) {  // RNE float->bf16
    unsigned u = __float_as_uint(f);
    u += 0x7fffu + ((u >> 16) & 1u);
    return (unsigned short)(u >> 16);
}
DEVINL float bf2f(unsigned short s) { return __uint_as_float(((unsigned)s) << 16); }

// blocks 0..63: transpose + bf16-convert weights (WT[col][k] layouts).
// blocks 64..95: zero cnt | hsumR (replaces hipMemsetAsync).
__global__ __launch_bounds__(256) void k_w(
    const float* __restrict__ Wenc, const float* __restrict__ WM,
    const float* __restrict__ WU,
    unsigned short* __restrict__ WencT, unsigned short* __restrict__ WM1T,
    unsigned short* __restrict__ WM2T, unsigned short* __restrict__ WUT,
    int* __restrict__ zbase, int zn)
{
    if (blockIdx.x < 64) {
        int tid = blockIdx.x * 256 + threadIdx.x;
        const int nt = 64 * 256;
        for (int i = tid; i < 128 * 128; i += nt) {
            int c = i >> 7, k = i & 127;
            WencT[c * 128 + k] = f2bf(Wenc[(1 + k) * 128 + c]);  // rows 1..128
            WM1T[c * 128 + k]  = f2bf(WM[k * 128 + c]);
            WM2T[c * 128 + k]  = f2bf(WM[(128 + k) * 128 + c]);
        }
        for (int i = tid; i < 128 * 256; i += nt) {
            int c = i >> 8, k = i & 255;
            WUT[c * 256 + k] = f2bf(WU[k * 128 + c]);
        }
    } else {
        for (int i = (blockIdx.x - 64) * 256 + threadIdx.x; i < zn; i += 32 * 256)
            zbase[i] = 0;
    }
}

// ---- MFMA structure: block = 16 nodes, 4 waves split the 128 output cols
// (wave w -> t8 in {2w,2w+1} -> cols [32w,32w+32)).
// D: node = lane&15, col = t8*16 + (lane>>4)*4 + r.

// blocks [0,nzq): z = relu([x,pre_h]@W_enc+b) -> zb;  Q = z@WM2 -> Qb.
// blocks [nzq,..): edge bucket scatter (independent work, overlapped).
__global__ __launch_bounds__(256) void k_zq(
    const float* __restrict__ x, const float* __restrict__ preh,
    const unsigned short* __restrict__ WencT, const float* __restrict__ Wenc,
    const float* __restrict__ benc, const unsigned short* __restrict__ WM2T,
    unsigned short* __restrict__ zb, unsigned short* __restrict__ Qb,
    int N, int nzq,
    const int* __restrict__ ei, const float* __restrict__ attr,
    int* __restrict__ cnt, int2* __restrict__ bucket, int E)
{
    if ((int)blockIdx.x >= nzq) {  // ---- scatter part
        int e = ((int)blockIdx.x - nzq) * 256 + threadIdx.x;
        if (e >= E) return;
        int src = ei[e];
        int dst = ei[E + e];
        float a = attr[e];
        int slot = atomicAdd(&cnt[dst], 1);
        if (slot < BCAP)
            bucket[(size_t)dst * BCAP + slot] = make_int2(src, __float_as_int(a));
        return;
    }
    __shared__ __align__(16) unsigned short zl[16][136];
    int t = threadIdx.x;
    int wave = t >> 6, lane = t & 63;
    int m = lane & 15, quad = lane >> 4;
    int node = (int)blockIdx.x * 16 + m;
    bool valid = node < N;
    int nodec = min(node, N - 1);
    // ---- phase A: z tile
    f32x4 acc[2] = {(f32x4)0.f, (f32x4)0.f};
    const float* arow = preh + (size_t)nodec * 128;
#pragma unroll
    for (int kc = 0; kc < 4; ++kc) {
        int k0 = kc * 32 + quad * 8;
        float4 f0 = *(const float4*)(arow + k0);
        float4 f1 = *(const float4*)(arow + k0 + 4);
        short8 bfrag;
        bfrag[0] = (short)f2bf(f0.x); bfrag[1] = (short)f2bf(f0.y);
        bfrag[2] = (short)f2bf(f0.z); bfrag[3] = (short)f2bf(f0.w);
        bfrag[4] = (short)f2bf(f1.x); bfrag[5] = (short)f2bf(f1.y);
        bfrag[6] = (short)f2bf(f1.z); bfrag[7] = (short)f2bf(f1.w);
#pragma unroll
        for (int tt = 0; tt < 2; ++tt) {
            int t8 = wave * 2 + tt;
            short8 afrag = *(const short8*)(WencT + (size_t)(t8 * 16 + m) * 128 + k0);
            acc[tt] = __builtin_amdgcn_mfma_f32_16x16x32_bf16(afrag, bfrag, acc[tt], 0, 0, 0);
        }
    }
    float xv = x[nodec];
#pragma unroll
    for (int tt = 0; tt < 2; ++tt) {
        int col = (wave * 2 + tt) * 16 + quad * 4;
        float4 w0v = *(const float4*)(Wenc + col);  // row 0 of W_enc = x weights
        float4 bv  = *(const float4*)(benc + col);
        ushort4v o;
        o[0] = f2bf(fmaxf(acc[tt][0] + xv * w0v.x + bv.x, 0.f));
        o[1] = f2bf(fmaxf(acc[tt][1] + xv * w0v.y + bv.y, 0.f));
        o[2] = f2bf(fmaxf(acc[tt][2] + xv * w0v.z + bv.z, 0.f));
        o[3] = f2bf(fmaxf(acc[tt][3] + xv * w0v.w + bv.w, 0.f));
        if (valid) *(ushort4v*)(zb + (size_t)node * 128 + col) = o;
        *(ushort4v*)&zl[m][col] = o;  // stage for phase B
    }
    __syncthreads();
    // ---- phase B: Q from LDS z
    f32x4 aQ[2] = {(f32x4)0.f, (f32x4)0.f};
#pragma unroll
    for (int kc = 0; kc < 4; ++kc) {
        int k0 = kc * 32 + quad * 8;
        short8 bfrag = *(const short8*)&zl[m][k0];
#pragma unroll
        for (int tt = 0; tt < 2; ++tt) {
            int t8 = wave * 2 + tt;
            short8 a2 = *(const short8*)(WM2T + (size_t)(t8 * 16 + m) * 128 + k0);
            aQ[tt] = __builtin_amdgcn_mfma_f32_16x16x32_bf16(a2, bfrag, aQ[tt], 0, 0, 0);
        }
    }
    if (!valid) return;
    unsigned short* qrow = Qb + (size_t)node * 128;
#pragma unroll
    for (int tt = 0; tt < 2; ++tt) {
        int col = (wave * 2 + tt) * 16 + quad * 4;
        ushort4v oq;
        oq[0] = f2bf(aQ[tt][0]); oq[1] = f2bf(aQ[tt][1]);
        oq[2] = f2bf(aQ[tt][2]); oq[3] = f2bf(aQ[tt][3]);
        *(ushort4v*)(qrow + col) = oq;
    }
}

// Fused: bucket->LDS staging; gather-max; P GEMM (from z regs) + combine ->
// agg LDS; h = relu([z|agg]@W_U+b); y + hsum epilogues. NO device fences.
__global__ __launch_bounds__(256) void k_aggh(
    const unsigned short* __restrict__ zb, const unsigned short* __restrict__ Qb,
    const int2* __restrict__ bucket, const int* __restrict__ cnt,
    const float* __restrict__ w3, const float* __restrict__ bM,
    const unsigned short* __restrict__ WUT, const unsigned short* __restrict__ WM1T,
    const float* __restrict__ bU, const float* __restrict__ Wd,
    const float* __restrict__ bd,
    float* __restrict__ h, float* __restrict__ y, float* __restrict__ hsumR,
    int N)
{
    __shared__ int degs[16];
    __shared__ __align__(16) int2 eb[16][BCAP];       // 8 KB; reused as al below
    __shared__ __align__(16) float mac[16][132];
    __shared__ float ys[4][16];
    __shared__ float hsb[128];
    // al aliases eb: eb is dead after the gather phase (barrier-separated)
    unsigned short (*al)[136] = (unsigned short (*)[136])eb;

    int t = threadIdx.x;
    int bid16 = (int)blockIdx.x * 16;
    int wave = t >> 6, lane = t & 63;
    int m = lane & 15, quad = lane >> 4;
    int node = bid16 + m;
    bool valid = node < N;
    int nodec = min(node, N - 1);

    // issue z row loads early; reused by P GEMM, h GEMM, and y's z-term
    const unsigned short* arow = zb + (size_t)nodec * 128;
    short8 zfr[4];
#pragma unroll
    for (int kc = 0; kc < 4; ++kc)
        zfr[kc] = *(const short8*)(arow + kc * 32 + quad * 8);

    if (t < 16) degs[t] = min(cnt[min(bid16 + t, N - 1)], BCAP);
    __syncthreads();
    // stage bucket entries (coalesced, independent loads)
    for (int idx = t; idx < 16 * BCAP; idx += 256) {
        int nd = idx >> 6, sl = idx & (BCAP - 1);
        if (sl < degs[nd])
            eb[nd][sl] = bucket[(size_t)min(bid16 + nd, N - 1) * BCAP + sl];
    }
    __syncthreads();
    // gather-max: 16 threads/node, 8 cols each; entry addrs come from LDS
    {
        int il = t >> 4, c0 = (t & 15) * 8;
        int deg = degs[il];
        float w[8];
        {
            float4 wa = *(const float4*)(w3 + c0), wb = *(const float4*)(w3 + c0 + 4);
            w[0]=wa.x; w[1]=wa.y; w[2]=wa.z; w[3]=wa.w;
            w[4]=wb.x; w[5]=wb.y; w[6]=wb.z; w[7]=wb.w;
        }
        const float NI = __uint_as_float(0xff800000u);
        float a8[8];
#pragma unroll
        for (int u = 0; u < 8; ++u) a8[u] = NI;
        int j = 0;
        for (; j + 7 < deg; j += 8) {
            int2 e[8]; short8 q[8];
#pragma unroll
            for (int b = 0; b < 8; ++b) e[b] = eb[il][j + b];
#pragma unroll
            for (int b = 0; b < 8; ++b)
                q[b] = *(const short8*)(Qb + (size_t)e[b].x * 128 + c0);
#pragma unroll
            for (int b = 0; b < 8; ++b) {
                float a = __int_as_float(e[b].y);
#pragma unroll
                for (int u = 0; u < 8; ++u)
                    a8[u] = fmaxf(a8[u], fmaf(a, w[u], bf2f((unsigned short)q[b][u])));
            }
        }
        for (; j + 3 < deg; j += 4) {
            int2 e[4]; short8 q[4];
#pragma unroll
            for (int b = 0; b < 4; ++b) e[b] = eb[il][j + b];
#pragma unroll
            for (int b = 0; b < 4; ++b)
                q[b] = *(const short8*)(Qb + (size_t)e[b].x * 128 + c0);
#pragma unroll
            for (int b = 0; b < 4; ++b) {
                float a = __int_as_float(e[b].y);
#pragma unroll
                for (int u = 0; u < 8; ++u)
                    a8[u] = fmaxf(a8[u], fmaf(a, w[u], bf2f((unsigned short)q[b][u])));
            }
        }
        for (; j < deg; ++j) {
            int2 e0 = eb[il][j];
            float a = __int_as_float(e0.y);
            short8 q0 = *(const short8*)(Qb + (size_t)e0.x * 128 + c0);
#pragma unroll
            for (int u = 0; u < 8; ++u)
                a8[u] = fmaxf(a8[u], fmaf(a, w[u], bf2f((unsigned short)q0[u])));
        }
        *(f32x4*)&mac[il][c0]     = *(f32x4*)&a8[0];
        *(f32x4*)&mac[il][c0 + 4] = *(f32x4*)&a8[4];
    }
    __syncthreads();
    // P GEMM from z regs; combine agg = relu(P + bM + mac) -> al (bf16)
    {
        f32x4 accP[2] = {(f32x4)0.f, (f32x4)0.f};
#pragma unroll
        for (int kc = 0; kc < 4; ++kc) {
            int k0 = kc * 32 + quad * 8;
#pragma unroll
            for (int tt = 0; tt < 2; ++tt) {
                int t8 = wave * 2 + tt;
                short8 afrag = *(const short8*)(WM1T + (size_t)(t8 * 16 + m) * 128 + k0);
                accP[tt] = __builtin_amdgcn_mfma_f32_16x16x32_bf16(afrag, zfr[kc], accP[tt], 0, 0, 0);
            }
        }
#pragma unroll
        for (int tt = 0; tt < 2; ++tt) {
            int col = (wave * 2 + tt) * 16 + quad * 4;
            float4 bmv = *(const float4*)(bM + col);
            float4 mv  = *(const float4*)&mac[m][col];
            ushort4v o;  // deg==0: mac=-inf -> relu 0 (matches ref)
            o[0] = f2bf(fmaxf(accP[tt][0] + bmv.x + mv.x, 0.f));
            o[1] = f2bf(fmaxf(accP[tt][1] + bmv.y + mv.y, 0.f));
            o[2] = f2bf(fmaxf(accP[tt][2] + bmv.z + mv.z, 0.f));
            o[3] = f2bf(fmaxf(accP[tt][3] + bmv.w + mv.w, 0.f));
            *(ushort4v*)&al[m][col] = o;
        }
    }
    __syncthreads();
    // h GEMM (K=256: z from regs, agg from LDS) + fused epilogues
    f32x4 acc[2] = {(f32x4)0.f, (f32x4)0.f};
    float py = 0.f;
#pragma unroll
    for (int kc = 0; kc < 8; ++kc) {
        int k0 = kc * 32 + quad * 8;
        short8 bfrag;
        if (kc < 4) {
            bfrag = zfr[kc];
            if (wave == 0) {  // z·Wd[:128] term (each (kc,quad) k-slice once)
                float4 wa = *(const float4*)(Wd + k0);
                float4 wb = *(const float4*)(Wd + k0 + 4);
                py += bf2f((unsigned short)bfrag[0]) * wa.x
                    + bf2f((unsigned short)bfrag[1]) * wa.y
                    + bf2f((unsigned short)bfrag[2]) * wa.z
                    + bf2f((unsigned short)bfrag[3]) * wa.w
                    + bf2f((unsigned short)bfrag[4]) * wb.x
                    + bf2f((unsigned short)bfrag[5]) * wb.y
                    + bf2f((unsigned short)bfrag[6]) * wb.z
                    + bf2f((unsigned short)bfrag[7]) * wb.w;
            }
        } else {
            bfrag = *(const short8*)&al[m][(kc - 4) * 32 + quad * 8];
        }
#pragma unroll
        for (int tt = 0; tt < 2; ++tt) {
            int t8 = wave * 2 + tt;
            short8 afrag = *(const short8*)(WUT + (size_t)(t8 * 16 + m) * 256 + k0);
            acc[tt] = __builtin_amdgcn_mfma_f32_16x16x32_bf16(afrag, bfrag, acc[tt], 0, 0, 0);
        }
    }
    const float* Wdh = Wd + 128;
    float* orow = h + (size_t)nodec * 128;
#pragma unroll
    for (int tt = 0; tt < 2; ++tt) {
        int col = (wave * 2 + tt) * 16 + quad * 4;
        float4 bv = *(const float4*)(bU + col);
        float4 o;  // zeroed for invalid nodes so hsum stays exact
        o.x = valid ? fmaxf(acc[tt][0] + bv.x, 0.f) : 0.f;
        o.y = valid ? fmaxf(acc[tt][1] + bv.y, 0.f) : 0.f;
        o.z = valid ? fmaxf(acc[tt][2] + bv.z, 0.f) : 0.f;
        o.w = valid ? fmaxf(acc[tt][3] + bv.w, 0.f) : 0.f;
        if (valid) *(float4*)(orow + col) = o;
        float4 wd = *(const float4*)(Wdh + col);
        py += o.x * wd.x + o.y * wd.y + o.z * wd.z + o.w * wd.w;
        float4 s = o;  // sum over the 16 m-lanes (same cols, different nodes)
#pragma unroll
        for (int mask = 1; mask <= 8; mask <<= 1) {
            s.x += __shfl_xor(s.x, mask, 64);
            s.y += __shfl_xor(s.y, mask, 64);
            s.z += __shfl_xor(s.z, mask, 64);
            s.w += __shfl_xor(s.w, mask, 64);
        }
        if (m == 0) *(float4*)&hsb[col] = s;  // (t8,quad) slots disjoint
    }
    py += __shfl_xor(py, 16, 64);
    py += __shfl_xor(py, 32, 64);
    if (lane < 16) ys[wave][lane] = py;
    __syncthreads();
    if (t < 16 && bid16 + t < N)
        y[bid16 + t] = ys[0][t] + ys[1][t] + ys[2][t] + ys[3][t] + bd[0];
    if (t < 128)
        atomicAdd(&hsumR[((int)blockIdx.x & (NREP - 1)) * 128 + t], hsb[t]);
}

// tau = (sum_r hsumR[r]/N) . (W_term[0:128] + W_term[128:256]) + b_term
__global__ __launch_bounds__(128) void k_tau(
    const float* __restrict__ hsumR, const float* __restrict__ Wt,
    const float* __restrict__ bt, float* __restrict__ tau, int N)
{
    __shared__ float sd[128];
    int t = threadIdx.x;
    float s = 0.f;
#pragma unroll
    for (int r = 0; r < NREP; ++r) s += hsumR[r * 128 + t];
    float v = s * (1.f / (float)N) * (Wt[t] + Wt[128 + t]);
    sd[t] = v;
    __syncthreads();
    for (int o = 64; o > 0; o >>= 1) {
        if (t < o) sd[t] += sd[t + o];
        __syncthreads();
    }
    if (t == 0) tau[0] = sd[0] + bt[0];
}

extern "C" void kernel_launch(void* const* d_in, const int* in_sizes, int n_in,
                              void* d_out, int out_size, void* d_ws, size_t ws_size,
                              hipStream_t stream)
{
    const float* x     = (const float*)d_in[0];
    const float* preh  = (const float*)d_in[1];
    const int*   ei    = (const int*)d_in[2];
    const float* attr  = (const float*)d_in[3];
    const float* Wenc  = (const float*)d_in[4];
    const float* benc  = (const float*)d_in[5];
    const float* WM    = (const float*)d_in[6];
    const float* bM    = (const float*)d_in[7];
    const float* WU    = (const float*)d_in[8];
    const float* bU    = (const float*)d_in[9];
    const float* Wd    = (const float*)d_in[10];
    const float* bd    = (const float*)d_in[11];
    const float* Wterm = (const float*)d_in[12];
    const float* bterm = (const float*)d_in[13];
    int N = in_sizes[0];
    int E = in_sizes[3];

    char* wp = (char*)d_ws;
    unsigned short* zb    = (unsigned short*)wp; wp += (size_t)N * 128 * 2;
    unsigned short* Qb    = (unsigned short*)wp; wp += (size_t)N * 128 * 2;
    int2*           bucket= (int2*)wp;           wp += (size_t)N * BCAP * 8;
    int*            cnt   = (int*)wp;            wp += (size_t)N * 4;
    float*          hsumR = (float*)wp;          wp += NREP * 128 * 4;
    unsigned short* WencT = (unsigned short*)wp; wp += 128 * 128 * 2;
    unsigned short* WM1T  = (unsigned short*)wp; wp += 128 * 128 * 2;
    unsigned short* WM2T  = (unsigned short*)wp; wp += 128 * 128 * 2;
    unsigned short* WUT   = (unsigned short*)wp; wp += 128 * 256 * 2;

    float* hout = (float*)d_out;
    float* yout = hout + (size_t)N * 128;
    float* tau  = yout + N;

    int nb16 = (N + 15) / 16;
    int sb = (E + 255) / 256;
    int zn = N + NREP * 128;  // cnt | hsumR (contiguous ints)

    k_w<<<96, 256, 0, stream>>>(Wenc, WM, WU, WencT, WM1T, WM2T, WUT,
                                cnt, zn);
    k_zq<<<nb16 + sb, 256, 0, stream>>>(x, preh, WencT, Wenc, benc, WM2T,
                                        zb, Qb, N, nb16,
                                        ei, attr, cnt, bucket, E);
    k_aggh<<<nb16, 256, 0, stream>>>(zb, Qb, bucket, cnt, WM + 256 * 128, bM,
                                     WUT, WM1T, bU, Wd, bd,
                                     hout, yout, hsumR, N);
    k_tau<<<1, 128, 0, stream>>>(hsumR, Wterm, bterm, tau, N);
}

// Round 10
// 251.653 us; speedup vs baseline: 2.2919x; 1.0333x over previous
//
#include <hip/hip_runtime.h>

#define DEVINL __device__ __forceinline__
#define BCAP 64   // bucket capacity per node; deg~Poisson(12.8), P(>64)~3e-23
#define NREP 64   // hsum atomic replicas (contention / 64)

typedef __attribute__((ext_vector_type(8))) short short8;
typedef __attribute__((ext_vector_type(4))) float f32x4;
typedef __attribute__((ext_vector_type(4))) unsigned short ushort4v;

DEVINL unsigned short f2bf(float f) {  // RNE float->bf16
    unsigned u = __float_as_uint(f);
    u += 0x7fffu + ((u >> 16) & 1u);
    return (unsigned short)(u >> 16);
}
DEVINL float bf2f(unsigned short s) { return __uint_as_float(((unsigned)s) << 16); }

// blocks 0..63: transpose + bf16-convert weights (WT[col][k] layouts).
// blocks 64.. : bucket scatter, 4B packed entries (src<<16 | bf16(attr)).
__global__ __launch_bounds__(256) void k_prep(
    const float* __restrict__ Wenc, const float* __restrict__ WM,
    const float* __restrict__ WU,
    unsigned short* __restrict__ WencT, unsigned short* __restrict__ WM1T,
    unsigned short* __restrict__ WM2T, unsigned short* __restrict__ WUT,
    const int* __restrict__ ei, const float* __restrict__ attr,
    int* __restrict__ cnt, unsigned* __restrict__ bucket, int E)
{
    if (blockIdx.x < 64) {
        int tid = blockIdx.x * 256 + threadIdx.x;
        const int nt = 64 * 256;
        for (int i = tid; i < 128 * 128; i += nt) {
            int c = i >> 7, k = i & 127;
            WencT[c * 128 + k] = f2bf(Wenc[(1 + k) * 128 + c]);  // rows 1..128
            WM1T[c * 128 + k]  = f2bf(WM[k * 128 + c]);
            WM2T[c * 128 + k]  = f2bf(WM[(128 + k) * 128 + c]);
        }
        for (int i = tid; i < 128 * 256; i += nt) {
            int c = i >> 8, k = i & 255;
            WUT[c * 256 + k] = f2bf(WU[k * 128 + c]);
        }
    } else {
        int e = ((int)blockIdx.x - 64) * 256 + threadIdx.x;
        if (e >= E) return;
        int src = ei[e];
        int dst = ei[E + e];
        float a = attr[e];
        int slot = atomicAdd(&cnt[dst], 1);
        if (slot < BCAP)  // one 64B line holds 16 entries: L2 merges per-dst
            bucket[(size_t)dst * BCAP + slot] = ((unsigned)src << 16) | f2bf(a);
    }
}

// ---- MFMA structure: block = 16 nodes, 4 waves split the 128 output cols
// (wave w -> t8 in {2w,2w+1} -> cols [32w,32w+32)).
// D: node = lane&15, col = t8*16 + (lane>>4)*4 + r.

// z = relu([x,pre_h]@W_enc+b) -> zb;  Q = z@WM2 -> Qb.  Pure streaming GEMM.
__global__ __launch_bounds__(256) void k_zq(
    const float* __restrict__ x, const float* __restrict__ preh,
    const unsigned short* __restrict__ WencT, const float* __restrict__ Wenc,
    const float* __restrict__ benc, const unsigned short* __restrict__ WM2T,
    unsigned short* __restrict__ zb, unsigned short* __restrict__ Qb, int N)
{
    __shared__ __align__(16) unsigned short zl[16][136];
    int t = threadIdx.x;
    int wave = t >> 6, lane = t & 63;
    int m = lane & 15, quad = lane >> 4;
    int node = (int)blockIdx.x * 16 + m;
    bool valid = node < N;
    int nodec = min(node, N - 1);
    // ---- phase A: z tile
    f32x4 acc[2] = {(f32x4)0.f, (f32x4)0.f};
    const float* arow = preh + (size_t)nodec * 128;
#pragma unroll
    for (int kc = 0; kc < 4; ++kc) {
        int k0 = kc * 32 + quad * 8;
        float4 f0 = *(const float4*)(arow + k0);
        float4 f1 = *(const float4*)(arow + k0 + 4);
        short8 bfrag;
        bfrag[0] = (short)f2bf(f0.x); bfrag[1] = (short)f2bf(f0.y);
        bfrag[2] = (short)f2bf(f0.z); bfrag[3] = (short)f2bf(f0.w);
        bfrag[4] = (short)f2bf(f1.x); bfrag[5] = (short)f2bf(f1.y);
        bfrag[6] = (short)f2bf(f1.z); bfrag[7] = (short)f2bf(f1.w);
#pragma unroll
        for (int tt = 0; tt < 2; ++tt) {
            int t8 = wave * 2 + tt;
            short8 afrag = *(const short8*)(WencT + (size_t)(t8 * 16 + m) * 128 + k0);
            acc[tt] = __builtin_amdgcn_mfma_f32_16x16x32_bf16(afrag, bfrag, acc[tt], 0, 0, 0);
        }
    }
    float xv = x[nodec];
#pragma unroll
    for (int tt = 0; tt < 2; ++tt) {
        int col = (wave * 2 + tt) * 16 + quad * 4;
        float4 w0v = *(const float4*)(Wenc + col);  // row 0 of W_enc = x weights
        float4 bv  = *(const float4*)(benc + col);
        ushort4v o;
        o[0] = f2bf(fmaxf(acc[tt][0] + xv * w0v.x + bv.x, 0.f));
        o[1] = f2bf(fmaxf(acc[tt][1] + xv * w0v.y + bv.y, 0.f));
        o[2] = f2bf(fmaxf(acc[tt][2] + xv * w0v.z + bv.z, 0.f));
        o[3] = f2bf(fmaxf(acc[tt][3] + xv * w0v.w + bv.w, 0.f));
        if (valid) *(ushort4v*)(zb + (size_t)node * 128 + col) = o;
        *(ushort4v*)&zl[m][col] = o;  // stage for phase B
    }
    __syncthreads();
    // ---- phase B: Q from LDS z
    f32x4 aQ[2] = {(f32x4)0.f, (f32x4)0.f};
#pragma unroll
    for (int kc = 0; kc < 4; ++kc) {
        int k0 = kc * 32 + quad * 8;
        short8 bfrag = *(const short8*)&zl[m][k0];
#pragma unroll
        for (int tt = 0; tt < 2; ++tt) {
            int t8 = wave * 2 + tt;
            short8 a2 = *(const short8*)(WM2T + (size_t)(t8 * 16 + m) * 128 + k0);
            aQ[tt] = __builtin_amdgcn_mfma_f32_16x16x32_bf16(a2, bfrag, aQ[tt], 0, 0, 0);
        }
    }
    if (!valid) return;
    unsigned short* qrow = Qb + (size_t)node * 128;
#pragma unroll
    for (int tt = 0; tt < 2; ++tt) {
        int col = (wave * 2 + tt) * 16 + quad * 4;
        ushort4v oq;
        oq[0] = f2bf(aQ[tt][0]); oq[1] = f2bf(aQ[tt][1]);
        oq[2] = f2bf(aQ[tt][2]); oq[3] = f2bf(aQ[tt][3]);
        *(ushort4v*)(qrow + col) = oq;
    }
}

// Fused: bucket->LDS staging; gather-max; P GEMM (from z regs) + combine ->
// agg LDS; h = relu([z|agg]@W_U+b); y + hsum epilogues. NO device fences.
__global__ __launch_bounds__(256) void k_aggh(
    const unsigned short* __restrict__ zb, const unsigned short* __restrict__ Qb,
    const unsigned* __restrict__ bucket, const int* __restrict__ cnt,
    const float* __restrict__ w3, const float* __restrict__ bM,
    const unsigned short* __restrict__ WUT, const unsigned short* __restrict__ WM1T,
    const float* __restrict__ bU, const float* __restrict__ Wd,
    const float* __restrict__ bd,
    float* __restrict__ h, float* __restrict__ y, float* __restrict__ hsumR,
    int N)
{
    __shared__ int degs[16];
    __shared__ __align__(16) unsigned eb[16][68];   // 4.3 KB; row 272B
    __shared__ __align__(16) float mac[16][132];
    __shared__ float ys[4][16];
    __shared__ float hsb[128];
    // al aliases eb exactly (row 272B): eb dead after gather (barrier-separated)
    unsigned short (*al)[136] = (unsigned short (*)[136])eb;

    int t = threadIdx.x;
    int bid16 = (int)blockIdx.x * 16;
    int wave = t >> 6, lane = t & 63;
    int m = lane & 15, quad = lane >> 4;
    int node = bid16 + m;
    bool valid = node < N;
    int nodec = min(node, N - 1);

    // issue z row loads early; reused by P GEMM, h GEMM, and y's z-term
    const unsigned short* arow = zb + (size_t)nodec * 128;
    short8 zfr[4];
#pragma unroll
    for (int kc = 0; kc < 4; ++kc)
        zfr[kc] = *(const short8*)(arow + kc * 32 + quad * 8);

    if (t < 16) degs[t] = min(cnt[min(bid16 + t, N - 1)], BCAP);
    __syncthreads();
    // stage bucket entries (coalesced, independent loads)
    for (int idx = t; idx < 16 * BCAP; idx += 256) {
        int nd = idx >> 6, sl = idx & (BCAP - 1);
        if (sl < degs[nd])
            eb[nd][sl] = bucket[(size_t)min(bid16 + nd, N - 1) * BCAP + sl];
    }
    __syncthreads();
    // gather-max: 16 threads/node, 8 cols each; entry addrs come from LDS
    {
        int il = t >> 4, c0 = (t & 15) * 8;
        int deg = degs[il];
        float w[8];
        {
            float4 wa = *(const float4*)(w3 + c0), wb = *(const float4*)(w3 + c0 + 4);
            w[0]=wa.x; w[1]=wa.y; w[2]=wa.z; w[3]=wa.w;
            w[4]=wb.x; w[5]=wb.y; w[6]=wb.z; w[7]=wb.w;
        }
        const float NI = __uint_as_float(0xff800000u);
        float a8[8];
#pragma unroll
        for (int u = 0; u < 8; ++u) a8[u] = NI;
        int j = 0;
        for (; j + 7 < deg; j += 8) {
            unsigned e[8]; short8 q[8];
#pragma unroll
            for (int b = 0; b < 8; ++b) e[b] = eb[il][j + b];
#pragma unroll
            for (int b = 0; b < 8; ++b)
                q[b] = *(const short8*)(Qb + (size_t)(e[b] >> 16) * 128 + c0);
#pragma unroll
            for (int b = 0; b < 8; ++b) {
                float a = bf2f((unsigned short)(e[b] & 0xffffu));
#pragma unroll
                for (int u = 0; u < 8; ++u)
                    a8[u] = fmaxf(a8[u], fmaf(a, w[u], bf2f((unsigned short)q[b][u])));
            }
        }
        for (; j + 3 < deg; j += 4) {
            unsigned e[4]; short8 q[4];
#pragma unroll
            for (int b = 0; b < 4; ++b) e[b] = eb[il][j + b];
#pragma unroll
            for (int b = 0; b < 4; ++b)
                q[b] = *(const short8*)(Qb + (size_t)(e[b] >> 16) * 128 + c0);
#pragma unroll
            for (int b = 0; b < 4; ++b) {
                float a = bf2f((unsigned short)(e[b] & 0xffffu));
#pragma unroll
                for (int u = 0; u < 8; ++u)
                    a8[u] = fmaxf(a8[u], fmaf(a, w[u], bf2f((unsigned short)q[b][u])));
            }
        }
        for (; j < deg; ++j) {
            unsigned e0 = eb[il][j];
            float a = bf2f((unsigned short)(e0 & 0xffffu));
            short8 q0 = *(const short8*)(Qb + (size_t)(e0 >> 16) * 128 + c0);
#pragma unroll
            for (int u = 0; u < 8; ++u)
                a8[u] = fmaxf(a8[u], fmaf(a, w[u], bf2f((unsigned short)q0[u])));
        }
        *(f32x4*)&mac[il][c0]     = *(f32x4*)&a8[0];
        *(f32x4*)&mac[il][c0 + 4] = *(f32x4*)&a8[4];
    }
    __syncthreads();
    // P GEMM from z regs; combine agg = relu(P + bM + mac) -> al (bf16)
    {
        f32x4 accP[2] = {(f32x4)0.f, (f32x4)0.f};
#pragma unroll
        for (int kc = 0; kc < 4; ++kc) {
            int k0 = kc * 32 + quad * 8;
#pragma unroll
            for (int tt = 0; tt < 2; ++tt) {
                int t8 = wave * 2 + tt;
                short8 afrag = *(const short8*)(WM1T + (size_t)(t8 * 16 + m) * 128 + k0);
                accP[tt] = __builtin_amdgcn_mfma_f32_16x16x32_bf16(afrag, zfr[kc], accP[tt], 0, 0, 0);
            }
        }
        __syncthreads();  // all mac reads done before al (aliasing eb) writes? no: mac!=eb. Barrier orders eb reads (gather) vs al writes.
#pragma unroll
        for (int tt = 0; tt < 2; ++tt) {
            int col = (wave * 2 + tt) * 16 + quad * 4;
            float4 bmv = *(const float4*)(bM + col);
            float4 mv  = *(const float4*)&mac[m][col];
            ushort4v o;  // deg==0: mac=-inf -> relu 0 (matches ref)
            o[0] = f2bf(fmaxf(accP[tt][0] + bmv.x + mv.x, 0.f));
            o[1] = f2bf(fmaxf(accP[tt][1] + bmv.y + mv.y, 0.f));
            o[2] = f2bf(fmaxf(accP[tt][2] + bmv.z + mv.z, 0.f));
            o[3] = f2bf(fmaxf(accP[tt][3] + bmv.w + mv.w, 0.f));
            *(ushort4v*)&al[m][col] = o;
        }
    }
    __syncthreads();
    // h GEMM (K=256: z from regs, agg from LDS) + fused epilogues
    f32x4 acc[2] = {(f32x4)0.f, (f32x4)0.f};
    float py = 0.f;
#pragma unroll
    for (int kc = 0; kc < 8; ++kc) {
        int k0 = kc * 32 + quad * 8;
        short8 bfrag;
        if (kc < 4) {
            bfrag = zfr[kc];
            if (wave == 0) {  // z·Wd[:128] term (each (kc,quad) k-slice once)
                float4 wa = *(const float4*)(Wd + k0);
                float4 wb = *(const float4*)(Wd + k0 + 4);
                py += bf2f((unsigned short)bfrag[0]) * wa.x
                    + bf2f((unsigned short)bfrag[1]) * wa.y
                    + bf2f((unsigned short)bfrag[2]) * wa.z
                    + bf2f((unsigned short)bfrag[3]) * wa.w
                    + bf2f((unsigned short)bfrag[4]) * wb.x
                    + bf2f((unsigned short)bfrag[5]) * wb.y
                    + bf2f((unsigned short)bfrag[6]) * wb.z
                    + bf2f((unsigned short)bfrag[7]) * wb.w;
            }
        } else {
            bfrag = *(const short8*)&al[m][(kc - 4) * 32 + quad * 8];
        }
#pragma unroll
        for (int tt = 0; tt < 2; ++tt) {
            int t8 = wave * 2 + tt;
            short8 afrag = *(const short8*)(WUT + (size_t)(t8 * 16 + m) * 256 + k0);
            acc[tt] = __builtin_amdgcn_mfma_f32_16x16x32_bf16(afrag, bfrag, acc[tt], 0, 0, 0);
        }
    }
    const float* Wdh = Wd + 128;
    float* orow = h + (size_t)nodec * 128;
#pragma unroll
    for (int tt = 0; tt < 2; ++tt) {
        int col = (wave * 2 + tt) * 16 + quad * 4;
        float4 bv = *(const float4*)(bU + col);
        float4 o;  // zeroed for invalid nodes so hsum stays exact
        o.x = valid ? fmaxf(acc[tt][0] + bv.x, 0.f) : 0.f;
        o.y = valid ? fmaxf(acc[tt][1] + bv.y, 0.f) : 0.f;
        o.z = valid ? fmaxf(acc[tt][2] + bv.z, 0.f) : 0.f;
        o.w = valid ? fmaxf(acc[tt][3] + bv.w, 0.f) : 0.f;
        if (valid) *(float4*)(orow + col) = o;
        float4 wd = *(const float4*)(Wdh + col);
        py += o.x * wd.x + o.y * wd.y + o.z * wd.z + o.w * wd.w;
        float4 s = o;  // sum over the 16 m-lanes (same cols, different nodes)
#pragma unroll
        for (int mask = 1; mask <= 8; mask <<= 1) {
            s.x += __shfl_xor(s.x, mask, 64);
            s.y += __shfl_xor(s.y, mask, 64);
            s.z += __shfl_xor(s.z, mask, 64);
            s.w += __shfl_xor(s.w, mask, 64);
        }
        if (m == 0) *(float4*)&hsb[col] = s;  // (t8,quad) slots disjoint
    }
    py += __shfl_xor(py, 16, 64);
    py += __shfl_xor(py, 32, 64);
    if (lane < 16) ys[wave][lane] = py;
    __syncthreads();
    if (t < 16 && bid16 + t < N)
        y[bid16 + t] = ys[0][t] + ys[1][t] + ys[2][t] + ys[3][t] + bd[0];
    if (t < 128)
        atomicAdd(&hsumR[((int)blockIdx.x & (NREP - 1)) * 128 + t], hsb[t]);
}

// tau = (sum_r hsumR[r]/N) . (W_term[0:128] + W_term[128:256]) + b_term
__global__ __launch_bounds__(128) void k_tau(
    const float* __restrict__ hsumR, const float* __restrict__ Wt,
    const float* __restrict__ bt, float* __restrict__ tau, int N)
{
    __shared__ float sd[128];
    int t = threadIdx.x;
    float s = 0.f;
#pragma unroll
    for (int r = 0; r < NREP; ++r) s += hsumR[r * 128 + t];
    float v = s * (1.f / (float)N) * (Wt[t] + Wt[128 + t]);
    sd[t] = v;
    __syncthreads();
    for (int o = 64; o > 0; o >>= 1) {
        if (t < o) sd[t] += sd[t + o];
        __syncthreads();
    }
    if (t == 0) tau[0] = sd[0] + bt[0];
}

extern "C" void kernel_launch(void* const* d_in, const int* in_sizes, int n_in,
                              void* d_out, int out_size, void* d_ws, size_t ws_size,
                              hipStream_t stream)
{
    const float* x     = (const float*)d_in[0];
    const float* preh  = (const float*)d_in[1];
    const int*   ei    = (const int*)d_in[2];
    const float* attr  = (const float*)d_in[3];
    const float* Wenc  = (const float*)d_in[4];
    const float* benc  = (const float*)d_in[5];
    const float* WM    = (const float*)d_in[6];
    const float* bM    = (const float*)d_in[7];
    const float* WU    = (const float*)d_in[8];
    const float* bU    = (const float*)d_in[9];
    const float* Wd    = (const float*)d_in[10];
    const float* bd    = (const float*)d_in[11];
    const float* Wterm = (const float*)d_in[12];
    const float* bterm = (const float*)d_in[13];
    int N = in_sizes[0];
    int E = in_sizes[3];

    char* wp = (char*)d_ws;
    unsigned short* zb    = (unsigned short*)wp; wp += (size_t)N * 128 * 2;
    unsigned short* Qb    = (unsigned short*)wp; wp += (size_t)N * 128 * 2;
    unsigned*       bucket= (unsigned*)wp;       wp += (size_t)N * BCAP * 4;
    int*            cnt   = (int*)wp;            wp += (size_t)N * 4;
    float*          hsumR = (float*)wp;          wp += NREP * 128 * 4;
    unsigned short* WencT = (unsigned short*)wp; wp += 128 * 128 * 2;
    unsigned short* WM1T  = (unsigned short*)wp; wp += 128 * 128 * 2;
    unsigned short* WM2T  = (unsigned short*)wp; wp += 128 * 128 * 2;
    unsigned short* WUT   = (unsigned short*)wp; wp += 128 * 256 * 2;

    float* hout = (float*)d_out;
    float* yout = hout + (size_t)N * 128;
    float* tau  = yout + N;

    int nb16 = (N + 15) / 16;
    int sb = (E + 255) / 256;

    // zero cnt + hsumR (contiguous)
    hipMemsetAsync(cnt, 0, ((size_t)N + NREP * 128) * sizeof(int), stream);
    k_prep<<<64 + sb, 256, 0, stream>>>(Wenc, WM, WU, WencT, WM1T, WM2T, WUT,
                                        ei, attr, cnt, bucket, E);
    k_zq<<<nb16, 256, 0, stream>>>(x, preh, WencT, Wenc, benc, WM2T,
                                   zb, Qb, N);
    k_aggh<<<nb16, 256, 0, stream>>>(zb, Qb, bucket, cnt, WM + 256 * 128, bM,
                                     WUT, WM1T, bU, Wd, bd,
                                     hout, yout, hsumR, N);
    k_tau<<<1, 128, 0, stream>>>(hsumR, Wterm, bterm, tau, N);
}

// Round 11
// 250.811 us; speedup vs baseline: 2.2996x; 1.0034x over previous
//
#include <hip/hip_runtime.h>
#include <hip/hip_fp8.h>

#define DEVINL __device__ __forceinline__
#define BCAP 64   // bucket capacity per node; deg~Poisson(12.8), P(>64)~3e-23
#define NREP 64   // hsum atomic replicas (contention / 64)

typedef __attribute__((ext_vector_type(8))) short short8;
typedef __attribute__((ext_vector_type(4))) float f32x4;
typedef __attribute__((ext_vector_type(4))) unsigned short ushort4v;

DEVINL unsigned short f2bf(float f) {  // RNE float->bf16
    unsigned u = __float_as_uint(f);
    u += 0x7fffu + ((u >> 16) & 1u);
    return (unsigned short)(u >> 16);
}
DEVINL float bf2f(unsigned short s) { return __uint_as_float(((unsigned)s) << 16); }

DEVINL unsigned char f2e4(float f) {  // float -> fp8 e4m3 (OCP, HW cvt)
    __hip_fp8_e4m3 t(f);
    return (unsigned char)t.__x;
}
DEVINL float e42f(unsigned char b) {  // fp8 e4m3 -> float
    __hip_fp8_e4m3 t; t.__x = (__hip_fp8_storage_t)b;
    return (float)t;
}

// blocks 0..63: transpose + bf16-convert weights (WT[col][k] layouts).
// blocks 64.. : bucket scatter, 4B packed entries (src<<16 | bf16(attr)).
__global__ __launch_bounds__(256) void k_prep(
    const float* __restrict__ Wenc, const float* __restrict__ WM,
    const float* __restrict__ WU,
    unsigned short* __restrict__ WencT, unsigned short* __restrict__ WM1T,
    unsigned short* __restrict__ WM2T, unsigned short* __restrict__ WUT,
    const int* __restrict__ ei, const float* __restrict__ attr,
    int* __restrict__ cnt, unsigned* __restrict__ bucket, int E)
{
    if (blockIdx.x < 64) {
        int tid = blockIdx.x * 256 + threadIdx.x;
        const int nt = 64 * 256;
        for (int i = tid; i < 128 * 128; i += nt) {
            int c = i >> 7, k = i & 127;
            WencT[c * 128 + k] = f2bf(Wenc[(1 + k) * 128 + c]);  // rows 1..128
            WM1T[c * 128 + k]  = f2bf(WM[k * 128 + c]);
            WM2T[c * 128 + k]  = f2bf(WM[(128 + k) * 128 + c]);
        }
        for (int i = tid; i < 128 * 256; i += nt) {
            int c = i >> 8, k = i & 255;
            WUT[c * 256 + k] = f2bf(WU[k * 128 + c]);
        }
    } else {
        int e = ((int)blockIdx.x - 64) * 256 + threadIdx.x;
        if (e >= E) return;
        int src = ei[e];
        int dst = ei[E + e];
        float a = attr[e];
        int slot = atomicAdd(&cnt[dst], 1);
        if (slot < BCAP)  // one 64B line holds 16 entries: L2 merges per-dst
            bucket[(size_t)dst * BCAP + slot] = ((unsigned)src << 16) | f2bf(a);
    }
}

// ---- MFMA structure: block = 16 nodes, 4 waves split the 128 output cols
// (wave w -> t8 in {2w,2w+1} -> cols [32w,32w+32)).
// D: node = lane&15, col = t8*16 + (lane>>4)*4 + r.

// z = relu([x,pre_h]@W_enc+b) -> zb (bf16);  Q = z@WM2 -> Qb (fp8 e4m3).
__global__ __launch_bounds__(256) void k_zq(
    const float* __restrict__ x, const float* __restrict__ preh,
    const unsigned short* __restrict__ WencT, const float* __restrict__ Wenc,
    const float* __restrict__ benc, const unsigned short* __restrict__ WM2T,
    unsigned short* __restrict__ zb, unsigned char* __restrict__ Qb, int N)
{
    __shared__ __align__(16) unsigned short zl[16][136];
    int t = threadIdx.x;
    int wave = t >> 6, lane = t & 63;
    int m = lane & 15, quad = lane >> 4;
    int node = (int)blockIdx.x * 16 + m;
    bool valid = node < N;
    int nodec = min(node, N - 1);
    // ---- phase A: z tile
    f32x4 acc[2] = {(f32x4)0.f, (f32x4)0.f};
    const float* arow = preh + (size_t)nodec * 128;
#pragma unroll
    for (int kc = 0; kc < 4; ++kc) {
        int k0 = kc * 32 + quad * 8;
        float4 f0 = *(const float4*)(arow + k0);
        float4 f1 = *(const float4*)(arow + k0 + 4);
        short8 bfrag;
        bfrag[0] = (short)f2bf(f0.x); bfrag[1] = (short)f2bf(f0.y);
        bfrag[2] = (short)f2bf(f0.z); bfrag[3] = (short)f2bf(f0.w);
        bfrag[4] = (short)f2bf(f1.x); bfrag[5] = (short)f2bf(f1.y);
        bfrag[6] = (short)f2bf(f1.z); bfrag[7] = (short)f2bf(f1.w);
#pragma unroll
        for (int tt = 0; tt < 2; ++tt) {
            int t8 = wave * 2 + tt;
            short8 afrag = *(const short8*)(WencT + (size_t)(t8 * 16 + m) * 128 + k0);
            acc[tt] = __builtin_amdgcn_mfma_f32_16x16x32_bf16(afrag, bfrag, acc[tt], 0, 0, 0);
        }
    }
    float xv = x[nodec];
#pragma unroll
    for (int tt = 0; tt < 2; ++tt) {
        int col = (wave * 2 + tt) * 16 + quad * 4;
        float4 w0v = *(const float4*)(Wenc + col);  // row 0 of W_enc = x weights
        float4 bv  = *(const float4*)(benc + col);
        ushort4v o;
        o[0] = f2bf(fmaxf(acc[tt][0] + xv * w0v.x + bv.x, 0.f));
        o[1] = f2bf(fmaxf(acc[tt][1] + xv * w0v.y + bv.y, 0.f));
        o[2] = f2bf(fmaxf(acc[tt][2] + xv * w0v.z + bv.z, 0.f));
        o[3] = f2bf(fmaxf(acc[tt][3] + xv * w0v.w + bv.w, 0.f));
        if (valid) *(ushort4v*)(zb + (size_t)node * 128 + col) = o;
        *(ushort4v*)&zl[m][col] = o;  // stage for phase B
    }
    __syncthreads();
    // ---- phase B: Q from LDS z
    f32x4 aQ[2] = {(f32x4)0.f, (f32x4)0.f};
#pragma unroll
    for (int kc = 0; kc < 4; ++kc) {
        int k0 = kc * 32 + quad * 8;
        short8 bfrag = *(const short8*)&zl[m][k0];
#pragma unroll
        for (int tt = 0; tt < 2; ++tt) {
            int t8 = wave * 2 + tt;
            short8 a2 = *(const short8*)(WM2T + (size_t)(t8 * 16 + m) * 128 + k0);
            aQ[tt] = __builtin_amdgcn_mfma_f32_16x16x32_bf16(a2, bfrag, aQ[tt], 0, 0, 0);
        }
    }
    if (!valid) return;
    unsigned char* qrow = Qb + (size_t)node * 128;
#pragma unroll
    for (int tt = 0; tt < 2; ++tt) {
        int col = (wave * 2 + tt) * 16 + quad * 4;
        unsigned pk = (unsigned)f2e4(aQ[tt][0])
                    | ((unsigned)f2e4(aQ[tt][1]) << 8)
                    | ((unsigned)f2e4(aQ[tt][2]) << 16)
                    | ((unsigned)f2e4(aQ[tt][3]) << 24);
        *(unsigned*)(qrow + col) = pk;  // col % 4 == 0
    }
}

// Fused: bucket->LDS staging; gather-max (fp8 Q); P GEMM (from z regs) +
// combine -> agg LDS; h = relu([z|agg]@W_U+b); y + hsum epilogues.
__global__ __launch_bounds__(256) void k_aggh(
    const unsigned short* __restrict__ zb, const unsigned char* __restrict__ Qb,
    const unsigned* __restrict__ bucket, const int* __restrict__ cnt,
    const float* __restrict__ w3, const float* __restrict__ bM,
    const unsigned short* __restrict__ WUT, const unsigned short* __restrict__ WM1T,
    const float* __restrict__ bU, const float* __restrict__ Wd,
    const float* __restrict__ bd,
    float* __restrict__ h, float* __restrict__ y, float* __restrict__ hsumR,
    int N)
{
    __shared__ int degs[16];
    __shared__ __align__(16) unsigned eb[16][68];   // 4.3 KB; row 272B
    __shared__ __align__(16) float mac[16][132];
    __shared__ float ys[4][16];
    __shared__ float hsb[128];
    // al aliases eb exactly (row 272B): eb dead after gather (barrier-separated)
    unsigned short (*al)[136] = (unsigned short (*)[136])eb;

    int t = threadIdx.x;
    int bid16 = (int)blockIdx.x * 16;
    int wave = t >> 6, lane = t & 63;
    int m = lane & 15, quad = lane >> 4;
    int node = bid16 + m;
    bool valid = node < N;
    int nodec = min(node, N - 1);

    // issue z row loads early; reused by P GEMM, h GEMM, and y's z-term
    const unsigned short* arow = zb + (size_t)nodec * 128;
    short8 zfr[4];
#pragma unroll
    for (int kc = 0; kc < 4; ++kc)
        zfr[kc] = *(const short8*)(arow + kc * 32 + quad * 8);

    if (t < 16) degs[t] = min(cnt[min(bid16 + t, N - 1)], BCAP);
    __syncthreads();
    // stage bucket entries (coalesced, independent loads)
    for (int idx = t; idx < 16 * BCAP; idx += 256) {
        int nd = idx >> 6, sl = idx & (BCAP - 1);
        if (sl < degs[nd])
            eb[nd][sl] = bucket[(size_t)min(bid16 + nd, N - 1) * BCAP + sl];
    }
    __syncthreads();
    // gather-max: 16 threads/node, 8 cols each; fp8 Q rows (8B/thread/edge)
    {
        int il = t >> 4, c0 = (t & 15) * 8;
        int deg = degs[il];
        float w[8];
        {
            float4 wa = *(const float4*)(w3 + c0), wb = *(const float4*)(w3 + c0 + 4);
            w[0]=wa.x; w[1]=wa.y; w[2]=wa.z; w[3]=wa.w;
            w[4]=wb.x; w[5]=wb.y; w[6]=wb.z; w[7]=wb.w;
        }
        const float NI = __uint_as_float(0xff800000u);
        float a8[8];
#pragma unroll
        for (int u = 0; u < 8; ++u) a8[u] = NI;
        int j = 0;
        for (; j + 7 < deg; j += 8) {
            unsigned e[8]; uint2 q[8];
#pragma unroll
            for (int b = 0; b < 8; ++b) e[b] = eb[il][j + b];
#pragma unroll
            for (int b = 0; b < 8; ++b)
                q[b] = *(const uint2*)(Qb + (size_t)(e[b] >> 16) * 128 + c0);
#pragma unroll
            for (int b = 0; b < 8; ++b) {
                float a = bf2f((unsigned short)(e[b] & 0xffffu));
#pragma unroll
                for (int u = 0; u < 8; ++u) {
                    unsigned bits = ((u < 4 ? q[b].x >> (8 * u)
                                            : q[b].y >> (8 * (u - 4))) & 0xffu);
                    a8[u] = fmaxf(a8[u], fmaf(a, w[u], e42f((unsigned char)bits)));
                }
            }
        }
        for (; j + 3 < deg; j += 4) {
            unsigned e[4]; uint2 q[4];
#pragma unroll
            for (int b = 0; b < 4; ++b) e[b] = eb[il][j + b];
#pragma unroll
            for (int b = 0; b < 4; ++b)
                q[b] = *(const uint2*)(Qb + (size_t)(e[b] >> 16) * 128 + c0);
#pragma unroll
            for (int b = 0; b < 4; ++b) {
                float a = bf2f((unsigned short)(e[b] & 0xffffu));
#pragma unroll
                for (int u = 0; u < 8; ++u) {
                    unsigned bits = ((u < 4 ? q[b].x >> (8 * u)
                                            : q[b].y >> (8 * (u - 4))) & 0xffu);
                    a8[u] = fmaxf(a8[u], fmaf(a, w[u], e42f((unsigned char)bits)));
                }
            }
        }
        for (; j < deg; ++j) {
            unsigned e0 = eb[il][j];
            float a = bf2f((unsigned short)(e0 & 0xffffu));
            uint2 q0 = *(const uint2*)(Qb + (size_t)(e0 >> 16) * 128 + c0);
#pragma unroll
            for (int u = 0; u < 8; ++u) {
                unsigned bits = ((u < 4 ? q0.x >> (8 * u)
                                        : q0.y >> (8 * (u - 4))) & 0xffu);
                a8[u] = fmaxf(a8[u], fmaf(a, w[u], e42f((unsigned char)bits)));
            }
        }
        *(f32x4*)&mac[il][c0]     = *(f32x4*)&a8[0];
        *(f32x4*)&mac[il][c0 + 4] = *(f32x4*)&a8[4];
    }
    __syncthreads();
    // P GEMM from z regs; combine agg = relu(P + bM + mac) -> al (bf16)
    {
        f32x4 accP[2] = {(f32x4)0.f, (f32x4)0.f};
#pragma unroll
        for (int kc = 0; kc < 4; ++kc) {
            int k0 = kc * 32 + quad * 8;
#pragma unroll
            for (int tt = 0; tt < 2; ++tt) {
                int t8 = wave * 2 + tt;
                short8 afrag = *(const short8*)(WM1T + (size_t)(t8 * 16 + m) * 128 + k0);
                accP[tt] = __builtin_amdgcn_mfma_f32_16x16x32_bf16(afrag, zfr[kc], accP[tt], 0, 0, 0);
            }
        }
        // (eb reads all completed before the mac barrier; al writes are safe)
#pragma unroll
        for (int tt = 0; tt < 2; ++tt) {
            int col = (wave * 2 + tt) * 16 + quad * 4;
            float4 bmv = *(const float4*)(bM + col);
            float4 mv  = *(const float4*)&mac[m][col];
            ushort4v o;  // deg==0: mac=-inf -> relu 0 (matches ref)
            o[0] = f2bf(fmaxf(accP[tt][0] + bmv.x + mv.x, 0.f));
            o[1] = f2bf(fmaxf(accP[tt][1] + bmv.y + mv.y, 0.f));
            o[2] = f2bf(fmaxf(accP[tt][2] + bmv.z + mv.z, 0.f));
            o[3] = f2bf(fmaxf(accP[tt][3] + bmv.w + mv.w, 0.f));
            *(ushort4v*)&al[m][col] = o;
        }
    }
    __syncthreads();
    // h GEMM (K=256: z from regs, agg from LDS) + fused epilogues
    f32x4 acc[2] = {(f32x4)0.f, (f32x4)0.f};
    float py = 0.f;
#pragma unroll
    for (int kc = 0; kc < 8; ++kc) {
        int k0 = kc * 32 + quad * 8;
        short8 bfrag;
        if (kc < 4) {
            bfrag = zfr[kc];
            if (wave == 0) {  // z·Wd[:128] term (each (kc,quad) k-slice once)
                float4 wa = *(const float4*)(Wd + k0);
                float4 wb = *(const float4*)(Wd + k0 + 4);
                py += bf2f((unsigned short)bfrag[0]) * wa.x
                    + bf2f((unsigned short)bfrag[1]) * wa.y
                    + bf2f((unsigned short)bfrag[2]) * wa.z
                    + bf2f((unsigned short)bfrag[3]) * wa.w
                    + bf2f((unsigned short)bfrag[4]) * wb.x
                    + bf2f((unsigned short)bfrag[5]) * wb.y
                    + bf2f((unsigned short)bfrag[6]) * wb.z
                    + bf2f((unsigned short)bfrag[7]) * wb.w;
            }
        } else {
            bfrag = *(const short8*)&al[m][(kc - 4) * 32 + quad * 8];
        }
#pragma unroll
        for (int tt = 0; tt < 2; ++tt) {
            int t8 = wave * 2 + tt;
            short8 afrag = *(const short8*)(WUT + (size_t)(t8 * 16 + m) * 256 + k0);
            acc[tt] = __builtin_amdgcn_mfma_f32_16x16x32_bf16(afrag, bfrag, acc[tt], 0, 0, 0);
        }
    }
    const float* Wdh = Wd + 128;
    float* orow = h + (size_t)nodec * 128;
#pragma unroll
    for (int tt = 0; tt < 2; ++tt) {
        int col = (wave * 2 + tt) * 16 + quad * 4;
        float4 bv = *(const float4*)(bU + col);
        float4 o;  // zeroed for invalid nodes so hsum stays exact
        o.x = valid ? fmaxf(acc[tt][0] + bv.x, 0.f) : 0.f;
        o.y = valid ? fmaxf(acc[tt][1] + bv.y, 0.f) : 0.f;
        o.z = valid ? fmaxf(acc[tt][2] + bv.z, 0.f) : 0.f;
        o.w = valid ? fmaxf(acc[tt][3] + bv.w, 0.f) : 0.f;
        if (valid) *(float4*)(orow + col) = o;
        float4 wd = *(const float4*)(Wdh + col);
        py += o.x * wd.x + o.y * wd.y + o.z * wd.z + o.w * wd.w;
        float4 s = o;  // sum over the 16 m-lanes (same cols, different nodes)
#pragma unroll
        for (int mask = 1; mask <= 8; mask <<= 1) {
            s.x += __shfl_xor(s.x, mask, 64);
            s.y += __shfl_xor(s.y, mask, 64);
            s.z += __shfl_xor(s.z, mask, 64);
            s.w += __shfl_xor(s.w, mask, 64);
        }
        if (m == 0) *(float4*)&hsb[col] = s;  // (t8,quad) slots disjoint
    }
    py += __shfl_xor(py, 16, 64);
    py += __shfl_xor(py, 32, 64);
    if (lane < 16) ys[wave][lane] = py;
    __syncthreads();
    if (t < 16 && bid16 + t < N)
        y[bid16 + t] = ys[0][t] + ys[1][t] + ys[2][t] + ys[3][t] + bd[0];
    if (t < 128)
        atomicAdd(&hsumR[((int)blockIdx.x & (NREP - 1)) * 128 + t], hsb[t]);
}

// tau = (sum_r hsumR[r]/N) . (W_term[0:128] + W_term[128:256]) + b_term
__global__ __launch_bounds__(128) void k_tau(
    const float* __restrict__ hsumR, const float* __restrict__ Wt,
    const float* __restrict__ bt, float* __restrict__ tau, int N)
{
    __shared__ float sd[128];
    int t = threadIdx.x;
    float s = 0.f;
#pragma unroll
    for (int r = 0; r < NREP; ++r) s += hsumR[r * 128 + t];
    float v = s * (1.f / (float)N) * (Wt[t] + Wt[128 + t]);
    sd[t] = v;
    __syncthreads();
    for (int o = 64; o > 0; o >>= 1) {
        if (t < o) sd[t] += sd[t + o];
        __syncthreads();
    }
    if (t == 0) tau[0] = sd[0] + bt[0];
}

extern "C" void kernel_launch(void* const* d_in, const int* in_sizes, int n_in,
                              void* d_out, int out_size, void* d_ws, size_t ws_size,
                              hipStream_t stream)
{
    const float* x     = (const float*)d_in[0];
    const float* preh  = (const float*)d_in[1];
    const int*   ei    = (const int*)d_in[2];
    const float* attr  = (const float*)d_in[3];
    const float* Wenc  = (const float*)d_in[4];
    const float* benc  = (const float*)d_in[5];
    const float* WM    = (const float*)d_in[6];
    const float* bM    = (const float*)d_in[7];
    const float* WU    = (const float*)d_in[8];
    const float* bU    = (const float*)d_in[9];
    const float* Wd    = (const float*)d_in[10];
    const float* bd    = (const float*)d_in[11];
    const float* Wterm = (const float*)d_in[12];
    const float* bterm = (const float*)d_in[13];
    int N = in_sizes[0];
    int E = in_sizes[3];

    char* wp = (char*)d_ws;
    unsigned short* zb    = (unsigned short*)wp; wp += (size_t)N * 128 * 2;
    unsigned char*  Qb    = (unsigned char*)wp;  wp += (size_t)N * 128;
    unsigned*       bucket= (unsigned*)wp;       wp += (size_t)N * BCAP * 4;
    int*            cnt   = (int*)wp;            wp += (size_t)N * 4;
    float*          hsumR = (float*)wp;          wp += NREP * 128 * 4;
    unsigned short* WencT = (unsigned short*)wp; wp += 128 * 128 * 2;
    unsigned short* WM1T  = (unsigned short*)wp; wp += 128 * 128 * 2;
    unsigned short* WM2T  = (unsigned short*)wp; wp += 128 * 128 * 2;
    unsigned short* WUT   = (unsigned short*)wp; wp += 128 * 256 * 2;

    float* hout = (float*)d_out;
    float* yout = hout + (size_t)N * 128;
    float* tau  = yout + N;

    int nb16 = (N + 15) / 16;
    int sb = (E + 255) / 256;

    // zero cnt + hsumR (contiguous)
    hipMemsetAsync(cnt, 0, ((size_t)N + NREP * 128) * sizeof(int), stream);
    k_prep<<<64 + sb, 256, 0, stream>>>(Wenc, WM, WU, WencT, WM1T, WM2T, WUT,
                                        ei, attr, cnt, bucket, E);
    k_zq<<<nb16, 256, 0, stream>>>(x, preh, WencT, Wenc, benc, WM2T,
                                   zb, Qb, N);
    k_aggh<<<nb16, 256, 0, stream>>>(zb, Qb, bucket, cnt, WM + 256 * 128, bM,
                                     WUT, WM1T, bU, Wd, bd,
                                     hout, yout, hsumR, N);
    k_tau<<<1, 128, 0, stream>>>(hsumR, Wterm, bterm, tau, N);
}